// Round 1
// baseline (660.095 us; speedup 1.0000x reference)
//
#include <hip/hip_runtime.h>
#include <hip/hip_bf16.h>
#include <hip/hip_fp16.h>

// Bidirectional char-LSTM + masked max-pool, fused into ONE kernel.
// 512 blocks = (batch=256) x (dir=2); each block runs one chain of T=512 steps.
// Weights held in VGPRs as packed fp16x2 (2 gate-rows per thread, K=178 padded to 184).
// h/x operand vector lives in LDS as half2; dot via v_dot2_f32_f16 (f32 accumulate).

#define TT 512
#define DD 50
#define HH 128
#define G4 512
#define KP 92   // padded half2 count: ceil(178/2)=89 -> 92 (23 x uint4)

typedef _Float16 h2_t __attribute__((ext_vector_type(2)));
typedef unsigned int u32;

static __device__ __forceinline__ u32 packh2(float lo, float hi) {
    union { h2_t h; u32 u; } cv;
    cv.h.x = (_Float16)lo;
    cv.h.y = (_Float16)hi;
    return cv.u;
}

static __device__ __forceinline__ float dot2(u32 a, u32 b, float c) {
    union { u32 u; h2_t h; } ca, cb;
    ca.u = a; cb.u = b;
#if __has_builtin(__builtin_amdgcn_fdot2)
    return __builtin_amdgcn_fdot2(ca.h, cb.h, c, false);
#else
    return c + (float)ca.h.x * (float)cb.h.x + (float)ca.h.y * (float)cb.h.y;
#endif
}

static __device__ __forceinline__ float fexp(float x) {
#if __has_builtin(__builtin_amdgcn_exp2f)
    return __builtin_amdgcn_exp2f(x * 1.44269504088896341f);
#else
    return __expf(x);
#endif
}
static __device__ __forceinline__ float frcp(float x) {
#if __has_builtin(__builtin_amdgcn_rcpf)
    return __builtin_amdgcn_rcpf(x);
#else
    return 1.0f / x;
#endif
}
static __device__ __forceinline__ float sigf(float x) {
    return frcp(1.f + fexp(-x));
}
static __device__ __forceinline__ float tanhf_(float x) {
    return 1.f - 2.f * frcp(fexp(2.f * x) + 1.f);
}

__global__ __launch_bounds__(256, 2)
void bilstm_maxpool_kernel(const int* __restrict__ idx,
                           const float* __restrict__ masks,
                           const float* __restrict__ emb,
                           const float* __restrict__ Wih_f, const float* __restrict__ Whh_f,
                           const float* __restrict__ bih_f, const float* __restrict__ bhh_f,
                           const float* __restrict__ Wih_b, const float* __restrict__ Whh_b,
                           const float* __restrict__ bih_b, const float* __restrict__ bhh_b,
                           float* __restrict__ out)
{
    __shared__ __align__(16) u32 hx[2][KP];  // [x(25 half2) | h(64 half2) | pad(3)]
    __shared__ float gates[G4];
    __shared__ int   idx_s[TT];
    __shared__ float pen_s[TT];

    const int tid = threadIdx.x;
    const int d   = blockIdx.x & 1;   // 0=fwd, 1=bwd
    const int b   = blockIdx.x >> 1;
    const int rev = d;

    const float* Wih = d ? Wih_b : Wih_f;
    const float* Whh = d ? Whh_b : Whh_f;
    const float* bih = d ? bih_b : bih_f;
    const float* bhh = d ? bhh_b : bhh_f;

    // ---- preload idx + mask-penalty rows into LDS; zero hx (h0 = 0, pads = 0)
    for (int t = tid; t < TT; t += 256) {
        idx_s[t] = idx[b * TT + t];
        pen_s[t] = (1.0f - masks[b * TT + t]) * 1e8f;
    }
    {
        u32* p = &hx[0][0];
        for (int k = tid; k < 2 * KP; k += 256) p[k] = 0u;
    }

    // ---- per-thread weights: gate rows r0 = tid (i/f), r1 = tid+256 (g/o)
    const int r0 = tid, r1 = tid + 256;
    u32 w0[KP], w1[KP];
#pragma unroll
    for (int k = 0; k < KP; ++k) {
        float x0, x1, y0, y1;
        if (k < 25) {                       // Wih part: halves 0..49
            x0 = Wih[r0 * DD + 2 * k]; x1 = Wih[r0 * DD + 2 * k + 1];
            y0 = Wih[r1 * DD + 2 * k]; y1 = Wih[r1 * DD + 2 * k + 1];
        } else if (k < 89) {                // Whh part: halves 50..177
            const int j = 2 * k - 50;
            x0 = Whh[r0 * HH + j]; x1 = Whh[r0 * HH + j + 1];
            y0 = Whh[r1 * HH + j]; y1 = Whh[r1 * HH + j + 1];
        } else {                            // pad
            x0 = x1 = y0 = y1 = 0.f;
        }
        w0[k] = packh2(x0, x1);
        w1[k] = packh2(y0, y1);
    }
    const float bias0 = bih[r0] + bhh[r0];
    const float bias1 = bih[r1] + bhh[r1];

    __syncthreads();

    // ---- first x tile into hx[0]
    const int jj = tid - 64;                // threads 64..88 handle x (25 half2)
    if (jj >= 0 && jj < 25) {
        const int t0  = rev ? (TT - 1) : 0;
        const int row = idx_s[t0];
        hx[0][jj] = packh2(emb[row * DD + 2 * jj], emb[row * DD + 2 * jj + 1]);
    }
    __syncthreads();

    float c0 = 0.f, c1 = 0.f, rm0 = -3e38f, rm1 = -3e38f;
    int cur = 0;

    for (int s = 0; s < TT; ++s) {
        const int t = rev ? (TT - 1 - s) : s;

        // prefetch next step's embedding row (latency hidden under the dots)
        float e0 = 0.f, e1 = 0.f;
        const bool pf = (jj >= 0 && jj < 25) && (s + 1 < TT);
        if (pf) {
            const int t1  = rev ? (TT - 2 - s) : (s + 1);
            const int row = idx_s[t1];
            e0 = emb[row * DD + 2 * jj];
            e1 = emb[row * DD + 2 * jj + 1];
        }

        // ---- phase A: 2 gate dots per thread, K = 184 halves
        float a0 = bias0, a1 = bias1, p0 = 0.f, p1 = 0.f;
        const uint4* hv = (const uint4*)(&hx[cur][0]);
#pragma unroll
        for (int q = 0; q < KP / 4; ++q) {
            const uint4 v = hv[q];
            a0 = dot2(w0[4*q+0], v.x, a0); a1 = dot2(w1[4*q+0], v.x, a1);
            p0 = dot2(w0[4*q+1], v.y, p0); p1 = dot2(w1[4*q+1], v.y, p1);
            a0 = dot2(w0[4*q+2], v.z, a0); a1 = dot2(w1[4*q+2], v.z, a1);
            p0 = dot2(w0[4*q+3], v.w, p0); p1 = dot2(w1[4*q+3], v.w, p1);
        }
        gates[r0] = a0 + p0;
        gates[r1] = a1 + p1;
        __syncthreads();

        // ---- phase B: threads 0..63 update c/h for 2 hidden dims each;
        //      threads 64..88 write the prefetched x into the other buffer
        if (tid < 64) {
            const int u2 = 2 * tid;
            const float i0 = gates[u2],          i1 = gates[u2 + 1];
            const float f0 = gates[HH + u2],     f1 = gates[HH + u2 + 1];
            const float g0 = gates[2*HH + u2],   g1 = gates[2*HH + u2 + 1];
            const float o0 = gates[3*HH + u2],   o1 = gates[3*HH + u2 + 1];
            c0 = sigf(f0) * c0 + sigf(i0) * tanhf_(g0);
            c1 = sigf(f1) * c1 + sigf(i1) * tanhf_(g1);
            const float hh0 = sigf(o0) * tanhf_(c0);
            const float hh1 = sigf(o1) * tanhf_(c1);
            const float p = pen_s[t];
            rm0 = fmaxf(rm0, hh0 - p);
            rm1 = fmaxf(rm1, hh1 - p);
            hx[cur ^ 1][25 + tid] = packh2(hh0, hh1);
        } else if (pf) {
            hx[cur ^ 1][jj] = packh2(e0, e1);
        }
        __syncthreads();
        cur ^= 1;
    }

    if (tid < 64) {
        out[b * 256 + d * HH + 2 * tid]     = rm0;
        out[b * 256 + d * HH + 2 * tid + 1] = rm1;
    }
}

extern "C" void kernel_launch(void* const* d_in, const int* in_sizes, int n_in,
                              void* d_out, int out_size, void* d_ws, size_t ws_size,
                              hipStream_t stream) {
    const int*   idx   = (const int*)d_in[0];
    const float* masks = (const float*)d_in[1];
    const float* emb   = (const float*)d_in[2];
    const float* Wih_f = (const float*)d_in[3];
    const float* Whh_f = (const float*)d_in[4];
    const float* bih_f = (const float*)d_in[5];
    const float* bhh_f = (const float*)d_in[6];
    const float* Wih_b = (const float*)d_in[7];
    const float* Whh_b = (const float*)d_in[8];
    const float* bih_b = (const float*)d_in[9];
    const float* bhh_b = (const float*)d_in[10];
    float* out = (float*)d_out;

    bilstm_maxpool_kernel<<<dim3(512), dim3(256), 0, stream>>>(
        idx, masks, emb,
        Wih_f, Whh_f, bih_f, bhh_f,
        Wih_b, Whh_b, bih_b, bhh_b,
        out);
}

// Round 2
// 628.984 us; speedup vs baseline: 1.0495x; 1.0495x over previous
//
#include <hip/hip_runtime.h>
#include <hip/hip_bf16.h>
#include <hip/hip_fp16.h>

// Bidirectional char-LSTM + masked max-pool, fused into ONE kernel.
// 512 blocks = (batch=256) x (dir=2); each block runs one chain of T=512 steps.
// 512 threads/block: each thread owns ONE gate row (of 4H=512) as packed
// fp16x2 in VGPRs (92 u32 -> fits a 128-VGPR budget; R1's 2-rows/thread
// variant spilled at 184 u32). h/x operand vector lives in LDS as fp16;
// dot via v_dot2_f32_f16 (f32 accumulate).

#define TT 512
#define DD 50
#define HH 128
#define KP4 23    // uint4 (8-half) groups per row: 23*8 = 184 halves (178 used)
#define KH 184    // padded half count of [x(50) | h(128) | pad(6)]

typedef _Float16 h2_t __attribute__((ext_vector_type(2)));
typedef unsigned int u32;

static __device__ __forceinline__ u32 packh2(float lo, float hi) {
    union { h2_t h; u32 u; } cv;
    cv.h.x = (_Float16)lo;
    cv.h.y = (_Float16)hi;
    return cv.u;
}

static __device__ __forceinline__ float dot2(u32 a, u32 b, float c) {
    union { u32 u; h2_t h; } ca, cb;
    ca.u = a; cb.u = b;
#if __has_builtin(__builtin_amdgcn_fdot2)
    return __builtin_amdgcn_fdot2(ca.h, cb.h, c, false);
#else
    return c + (float)ca.h.x * (float)cb.h.x + (float)ca.h.y * (float)cb.h.y;
#endif
}

static __device__ __forceinline__ float fexp(float x) {
#if __has_builtin(__builtin_amdgcn_exp2f)
    return __builtin_amdgcn_exp2f(x * 1.44269504088896341f);
#else
    return __expf(x);
#endif
}
static __device__ __forceinline__ float frcp(float x) {
#if __has_builtin(__builtin_amdgcn_rcpf)
    return __builtin_amdgcn_rcpf(x);
#else
    return 1.0f / x;
#endif
}
static __device__ __forceinline__ float sigf(float x) {
    return frcp(1.f + fexp(-x));
}
static __device__ __forceinline__ float tanhf_(float x) {
    return 1.f - 2.f * frcp(fexp(2.f * x) + 1.f);
}

__global__ __launch_bounds__(512, 4)
void bilstm_maxpool_kernel(const int* __restrict__ idx,
                           const float* __restrict__ masks,
                           const float* __restrict__ emb,
                           const float* __restrict__ Wih_f, const float* __restrict__ Whh_f,
                           const float* __restrict__ bih_f, const float* __restrict__ bhh_f,
                           const float* __restrict__ Wih_b, const float* __restrict__ Whh_b,
                           const float* __restrict__ bih_b, const float* __restrict__ bhh_b,
                           float* __restrict__ out)
{
    __shared__ __align__(16) _Float16 hx[2][KH];  // [x(50) | h(128) | pad(6)], x2 dbuf
    __shared__ float gates[4 * HH];
    __shared__ int   idx_s[TT];
    __shared__ float pen_s[TT];

    const int tid = threadIdx.x;
    const int d   = blockIdx.x & 1;   // 0=fwd, 1=bwd
    const int b   = blockIdx.x >> 1;
    const int rev = d;

    const float* Wih = d ? Wih_b : Wih_f;
    const float* Whh = d ? Whh_b : Whh_f;
    const float* bih = d ? bih_b : bih_f;
    const float* bhh = d ? bhh_b : bhh_f;

    // ---- preload idx + mask-penalty rows into LDS; zero hx (h0 = 0, pads = 0)
    if (tid < TT) {
        idx_s[tid] = idx[b * TT + tid];
        pen_s[tid] = (1.0f - masks[b * TT + tid]) * 1e8f;
    }
    {
        _Float16* p = &hx[0][0];
        for (int k = tid; k < 2 * KH; k += 512) p[k] = (_Float16)0.f;
    }

    // ---- per-thread weights: ONE gate row r = tid, packed as 92 half2
    const int r = tid;
    u32 w[4 * KP4];
#pragma unroll
    for (int k = 0; k < 4 * KP4; ++k) {
        float x0, x1;
        if (k < 25) {                       // Wih part: halves 0..49
            x0 = Wih[r * DD + 2 * k]; x1 = Wih[r * DD + 2 * k + 1];
        } else if (k < 89) {                // Whh part: halves 50..177
            const int j = 2 * k - 50;
            x0 = Whh[r * HH + j]; x1 = Whh[r * HH + j + 1];
        } else {                            // pad
            x0 = x1 = 0.f;
        }
        w[k] = packh2(x0, x1);
    }
    const float bias = bih[r] + bhh[r];

    __syncthreads();

    // ---- first x tile into hx[0]: threads 128..177 handle the 50 x-halves
    const int jj = tid - HH;                // 0..49 for the x-loader threads
    const bool is_x = (jj >= 0 && jj < DD);
    if (is_x) {
        const int t0 = rev ? (TT - 1) : 0;
        hx[0][jj] = (_Float16)emb[idx_s[t0] * DD + jj];
    }
    __syncthreads();

    float c0 = 0.f, rm0 = -3e38f;
    int cur = 0;

    for (int s = 0; s < TT; ++s) {
        const int t = rev ? (TT - 1 - s) : s;

        // prefetch next step's embedding value (latency hidden under the dots)
        float e = 0.f;
        const bool pf = is_x && (s + 1 < TT);
        if (pf) {
            const int t1 = rev ? (TT - 2 - s) : (s + 1);
            e = emb[idx_s[t1] * DD + jj];
        }

        // ---- phase A: 1 gate dot per thread, K = 184 halves, 4 accumulators
        float a0 = bias, a1 = 0.f, a2 = 0.f, a3 = 0.f;
        const uint4* hv = (const uint4*)(&hx[cur][0]);
#pragma unroll
        for (int q = 0; q < KP4; ++q) {
            const uint4 v = hv[q];
            a0 = dot2(w[4*q+0], v.x, a0);
            a1 = dot2(w[4*q+1], v.y, a1);
            a2 = dot2(w[4*q+2], v.z, a2);
            a3 = dot2(w[4*q+3], v.w, a3);
        }
        gates[r] = (a0 + a1) + (a2 + a3);
        __syncthreads();

        // ---- phase B: threads 0..127 update c/h for 1 hidden dim each;
        //      threads 128..177 write the prefetched x into the other buffer
        if (tid < HH) {
            const float i0 = gates[tid];
            const float f0 = gates[HH + tid];
            const float g0 = gates[2 * HH + tid];
            const float o0 = gates[3 * HH + tid];
            c0 = sigf(f0) * c0 + sigf(i0) * tanhf_(g0);
            const float h0 = sigf(o0) * tanhf_(c0);
            rm0 = fmaxf(rm0, h0 - pen_s[t]);
            hx[cur ^ 1][DD + tid] = (_Float16)h0;
        } else if (pf) {
            hx[cur ^ 1][jj] = (_Float16)e;
        }
        __syncthreads();
        cur ^= 1;
    }

    if (tid < HH) {
        out[b * 256 + d * HH + tid] = rm0;
    }
}

extern "C" void kernel_launch(void* const* d_in, const int* in_sizes, int n_in,
                              void* d_out, int out_size, void* d_ws, size_t ws_size,
                              hipStream_t stream) {
    const int*   idx   = (const int*)d_in[0];
    const float* masks = (const float*)d_in[1];
    const float* emb   = (const float*)d_in[2];
    const float* Wih_f = (const float*)d_in[3];
    const float* Whh_f = (const float*)d_in[4];
    const float* bih_f = (const float*)d_in[5];
    const float* bhh_f = (const float*)d_in[6];
    const float* Wih_b = (const float*)d_in[7];
    const float* Whh_b = (const float*)d_in[8];
    const float* bih_b = (const float*)d_in[9];
    const float* bhh_b = (const float*)d_in[10];
    float* out = (float*)d_out;

    bilstm_maxpool_kernel<<<dim3(512), dim3(512), 0, stream>>>(
        idx, masks, emb,
        Wih_f, Whh_f, bih_f, bhh_f,
        Wih_b, Whh_b, bih_b, bhh_b,
        out);
}

// Round 3
// 627.008 us; speedup vs baseline: 1.0528x; 1.0032x over previous
//
#include <hip/hip_runtime.h>
#include <hip/hip_bf16.h>
#include <hip/hip_fp16.h>

// Bidirectional char-LSTM + masked max-pool, fused into ONE kernel.
// 512 blocks = (batch=256) x (dir=2); each block runs one chain of T=512 steps.
// 512 threads/block: each thread owns ONE gate row (of 4H=512) as packed
// fp16x2 in VGPRs (92 u32). amdgpu_waves_per_eu(4,4) pins the allocator to
// the 128-VGPR budget (R2: launch_bounds min-occupancy let it aim for 8
// waves/EU = 64 VGPR and spill 80 MB to scratch).
// h/x operand vector lives in LDS as fp16; dot via v_dot2_f32_f16.

#define TT 512
#define DD 50
#define HH 128
#define KP4 23    // uint4 (8-half) groups per row: 23*8 = 184 halves (178 used)
#define KH 184    // padded half count of [x(50) | h(128) | pad(6)]

typedef _Float16 h2_t __attribute__((ext_vector_type(2)));
typedef unsigned int u32;

static __device__ __forceinline__ u32 packh2(float lo, float hi) {
    union { h2_t h; u32 u; } cv;
    cv.h.x = (_Float16)lo;
    cv.h.y = (_Float16)hi;
    return cv.u;
}

static __device__ __forceinline__ float dot2(u32 a, u32 b, float c) {
    union { u32 u; h2_t h; } ca, cb;
    ca.u = a; cb.u = b;
#if __has_builtin(__builtin_amdgcn_fdot2)
    return __builtin_amdgcn_fdot2(ca.h, cb.h, c, false);
#else
    return c + (float)ca.h.x * (float)cb.h.x + (float)ca.h.y * (float)cb.h.y;
#endif
}

static __device__ __forceinline__ float fexp(float x) {
#if __has_builtin(__builtin_amdgcn_exp2f)
    return __builtin_amdgcn_exp2f(x * 1.44269504088896341f);
#else
    return __expf(x);
#endif
}
static __device__ __forceinline__ float frcp(float x) {
#if __has_builtin(__builtin_amdgcn_rcpf)
    return __builtin_amdgcn_rcpf(x);
#else
    return 1.0f / x;
#endif
}
static __device__ __forceinline__ float sigf(float x) {
    return frcp(1.f + fexp(-x));
}
static __device__ __forceinline__ float tanhf_(float x) {
    return 1.f - 2.f * frcp(fexp(2.f * x) + 1.f);
}

__global__ __attribute__((amdgpu_flat_work_group_size(512, 512),
                          amdgpu_waves_per_eu(4, 4)))
void bilstm_maxpool_kernel(const int* __restrict__ idx,
                           const float* __restrict__ masks,
                           const float* __restrict__ emb,
                           const float* __restrict__ Wih_f, const float* __restrict__ Whh_f,
                           const float* __restrict__ bih_f, const float* __restrict__ bhh_f,
                           const float* __restrict__ Wih_b, const float* __restrict__ Whh_b,
                           const float* __restrict__ bih_b, const float* __restrict__ bhh_b,
                           float* __restrict__ out)
{
    __shared__ __align__(16) _Float16 hx[2][KH];  // [x(50) | h(128) | pad(6)], x2 dbuf
    __shared__ float gates[4 * HH];
    __shared__ int   idx_s[TT];
    __shared__ float pen_s[TT];

    const int tid = threadIdx.x;
    const int d   = blockIdx.x & 1;   // 0=fwd, 1=bwd
    const int b   = blockIdx.x >> 1;
    const int rev = d;

    const float* Wih = d ? Wih_b : Wih_f;
    const float* Whh = d ? Whh_b : Whh_f;
    const float* bih = d ? bih_b : bih_f;
    const float* bhh = d ? bhh_b : bhh_f;

    // ---- preload idx + mask-penalty rows into LDS; zero hx (h0 = 0, pads = 0)
    if (tid < TT) {
        idx_s[tid] = idx[b * TT + tid];
        pen_s[tid] = (1.0f - masks[b * TT + tid]) * 1e8f;
    }
    {
        _Float16* p = &hx[0][0];
        for (int k = tid; k < 2 * KH; k += 512) p[k] = (_Float16)0.f;
    }

    // ---- per-thread weights: ONE gate row r = tid, packed as 92 half2
    const int r = tid;
    u32 w[4 * KP4];
#pragma unroll
    for (int k = 0; k < 4 * KP4; ++k) {
        float x0, x1;
        if (k < 25) {                       // Wih part: halves 0..49
            x0 = Wih[r * DD + 2 * k]; x1 = Wih[r * DD + 2 * k + 1];
        } else if (k < 89) {                // Whh part: halves 50..177
            const int j = 2 * k - 50;
            x0 = Whh[r * HH + j]; x1 = Whh[r * HH + j + 1];
        } else {                            // pad
            x0 = x1 = 0.f;
        }
        w[k] = packh2(x0, x1);
    }
    const float bias = bih[r] + bhh[r];

    __syncthreads();

    // ---- first x tile into hx[0]: threads 128..177 handle the 50 x-halves
    const int jj = tid - HH;                // 0..49 for the x-loader threads
    const bool is_x = (jj >= 0 && jj < DD);
    if (is_x) {
        const int t0 = rev ? (TT - 1) : 0;
        hx[0][jj] = (_Float16)emb[idx_s[t0] * DD + jj];
    }
    __syncthreads();

    float c0 = 0.f, rm0 = -3e38f;
    int cur = 0;

    for (int s = 0; s < TT; ++s) {
        const int t = rev ? (TT - 1 - s) : s;

        // prefetch next step's embedding value (latency hidden under the dots)
        float e = 0.f;
        const bool pf = is_x && (s + 1 < TT);
        if (pf) {
            const int t1 = rev ? (TT - 2 - s) : (s + 1);
            e = emb[idx_s[t1] * DD + jj];
        }

        // ---- phase A: 1 gate dot per thread, K = 184 halves, 4 accumulators
        float a0 = bias, a1 = 0.f, a2 = 0.f, a3 = 0.f;
        const uint4* hv = (const uint4*)(&hx[cur][0]);
#pragma unroll
        for (int q = 0; q < KP4; ++q) {
            const uint4 v = hv[q];
            a0 = dot2(w[4*q+0], v.x, a0);
            a1 = dot2(w[4*q+1], v.y, a1);
            a2 = dot2(w[4*q+2], v.z, a2);
            a3 = dot2(w[4*q+3], v.w, a3);
        }
        gates[r] = (a0 + a1) + (a2 + a3);
        __syncthreads();

        // ---- phase B: threads 0..127 update c/h for 1 hidden dim each;
        //      threads 128..177 write the prefetched x into the other buffer
        if (tid < HH) {
            const float i0 = gates[tid];
            const float f0 = gates[HH + tid];
            const float g0 = gates[2 * HH + tid];
            const float o0 = gates[3 * HH + tid];
            c0 = sigf(f0) * c0 + sigf(i0) * tanhf_(g0);
            const float h0 = sigf(o0) * tanhf_(c0);
            rm0 = fmaxf(rm0, h0 - pen_s[t]);
            hx[cur ^ 1][DD + tid] = (_Float16)h0;
        } else if (pf) {
            hx[cur ^ 1][jj] = (_Float16)e;
        }
        __syncthreads();
        cur ^= 1;
    }

    if (tid < HH) {
        out[b * 256 + d * HH + tid] = rm0;
    }
}

extern "C" void kernel_launch(void* const* d_in, const int* in_sizes, int n_in,
                              void* d_out, int out_size, void* d_ws, size_t ws_size,
                              hipStream_t stream) {
    const int*   idx   = (const int*)d_in[0];
    const float* masks = (const float*)d_in[1];
    const float* emb   = (const float*)d_in[2];
    const float* Wih_f = (const float*)d_in[3];
    const float* Whh_f = (const float*)d_in[4];
    const float* bih_f = (const float*)d_in[5];
    const float* bhh_f = (const float*)d_in[6];
    const float* Wih_b = (const float*)d_in[7];
    const float* Whh_b = (const float*)d_in[8];
    const float* bih_b = (const float*)d_in[9];
    const float* bhh_b = (const float*)d_in[10];
    float* out = (float*)d_out;

    bilstm_maxpool_kernel<<<dim3(512), dim3(512), 0, stream>>>(
        idx, masks, emb,
        Wih_f, Whh_f, bih_f, bhh_f,
        Wih_b, Whh_b, bih_b, bhh_b,
        out);
}